// Round 4
// baseline (4953.940 us; speedup 1.0000x reference)
//
#include <hip/hip_runtime.h>
#include <hip/hip_bf16.h>

// ---------------------------------------------------------------------------
// LIIF query_image fused kernel for MI355X (gfx950).  Round 3 (resubmit - R3
// never ran: GPU acquisition timeout).
// Split-precision bf16 MFMA (hi/lo, 3 products) ~= fp32 accuracy.
// R3 vs R1: __launch_bounds__(512,2) (256-VGPR budget), explicit 2-stage
// register prefetch pipeline for A(LDS)/B(global) fragments in every layer.
// Geometry back to TM=128 (12 MFMA per 4 B-loads), 1024 blocks, 1 block/CU.
// ---------------------------------------------------------------------------

typedef __attribute__((ext_vector_type(8)))  short   short8_t;
typedef __attribute__((ext_vector_type(8)))  __bf16  bf16x8;
typedef __attribute__((ext_vector_type(16))) float   f32x16;
typedef __attribute__((ext_vector_type(4)))  float   float4_t;

union Frag8 { short8_t s; bf16x8 b; };

#define EPS_SHIFT 1e-6f
#define EPS_AREA  1e-9f

constexpr int Bc = 2, Cc = 128, Hc = 128, Wc = 128, HLc = 64, WLc = 64;
constexpr int K0P = 272;          // layer0 K padded: 262 -> 272 (17 k-chunks of 16)
constexpr int TM = 128;           // queries per block
constexpr int THREADS = 512;      // 8 waves: 2(M) x 4(N)
constexpr int NKB = K0P / 8;      // 34 k-blocks of 8 in act buffer
constexpr int KBS = TM * 16;      // 2048 B per k-block per plane
constexpr int PLANE = NKB * KBS;  // 69632 B  (hi plane; lo plane follows)
constexpr int LDS_WT = 2 * PLANE;              // offset of weight table
constexpr int LDS_TOTAL = LDS_WT + 4 * TM * 4; // + wtab[4][128] = 141312 B

// workspace layout
constexpr size_t OFF_FEATT = 0;
constexpr size_t SZ_FEATT  = (size_t)Bc * Hc * Wc * Cc * 4;    // 16 MB
constexpr size_t OFF_LRT   = OFF_FEATT + SZ_FEATT;
constexpr size_t SZ_LRT    = (size_t)Bc * HLc * WLc * Cc * 4;  // 4 MB
constexpr size_t OFF_WT0   = OFF_LRT + SZ_LRT;
constexpr size_t PS0       = (size_t)256 * K0P * 2;            // per-plane bytes
constexpr size_t OFF_WT1   = OFF_WT0 + 2 * PS0;
constexpr size_t PS1       = (size_t)256 * 256 * 2;
constexpr size_t OFF_WT2   = OFF_WT1 + 2 * PS1;
constexpr size_t OFF_WT3   = OFF_WT2 + 2 * PS1;
constexpr size_t OFF_WT4   = OFF_WT3 + 2 * PS1;
constexpr size_t PS4       = (size_t)32 * 256 * 2;

// ---------------------------------------------------------------------------

__device__ __forceinline__ unsigned short bf16_rne(float x) {
    unsigned u = __float_as_uint(x);
    unsigned r = (u + 0x7FFFu + ((u >> 16) & 1u)) >> 16;
    return (unsigned short)r;
}

// x = hi + lo + eps, |eps| ~ 2^-17 |x|.  hi = truncated bf16, lo = rne(bf16(rem)).
__device__ __forceinline__ void split2(float v, unsigned short& hi, unsigned short& lo) {
    unsigned u = __float_as_uint(v) & 0xFFFF0000u;
    hi = (unsigned short)(u >> 16);
    lo = bf16_rne(v - __uint_as_float(u));
}

// byte offset of the 8-k group (row, kb) inside a plane (swizzled)
__device__ __forceinline__ int lds_grp(int row, int kb) {
    return kb * KBS + ((row * 16) ^ ((kb & 7) << 4));
}

// nearest-gather index math, exactly mirroring the reference formulas
__device__ __forceinline__ void calc_idx(float c0, float c1, int s,
                                         int& iy, int& ix, int& liy, int& lix,
                                         float& rel0, float& rel1) {
    const float rx = 1.0f / Hc, ry = 1.0f / Wc;
    const float vx = (s & 2) ? 1.0f : -1.0f;   // s: 0..3 = (vx,vy) in (-1,-1),(-1,1),(1,-1),(1,1)
    const float vy = (s & 1) ? 1.0f : -1.0f;
    const float sh0 = vx * rx + EPS_SHIFT;
    const float sh1 = vy * ry + EPS_SHIFT;
    float cc0 = fminf(fmaxf(c0 + sh0, -1.0f + 1e-6f), 1.0f - 1e-6f);
    float cc1 = fminf(fmaxf(c1 + sh1, -1.0f + 1e-6f), 1.0f - 1e-6f);
    iy  = min(max((int)floorf(((cc0 + 1.0f) * (float)Hc  - 1.0f) * 0.5f + 0.5f), 0), Hc  - 1);
    ix  = min(max((int)floorf(((cc1 + 1.0f) * (float)Wc  - 1.0f) * 0.5f + 0.5f), 0), Wc  - 1);
    liy = min(max((int)floorf(((cc0 + 1.0f) * (float)HLc - 1.0f) * 0.5f + 0.5f), 0), HLc - 1);
    lix = min(max((int)floorf(((cc1 + 1.0f) * (float)WLc - 1.0f) * 0.5f + 0.5f), 0), WLc - 1);
    const float qc0 = -1.0f + (2.0f * (float)iy + 1.0f) / (float)Hc;
    const float qc1 = -1.0f + (2.0f * (float)ix + 1.0f) / (float)Wc;
    rel0 = (c0 - qc0) * (float)Hc;   // rel uses ORIGINAL coord
    rel1 = (c1 - qc1) * (float)Wc;
}

// gather 32 contiguous channels (NHWC) -> hi/lo planes at k-blocks kbBase..+3
__device__ __forceinline__ void gather_write(const float* __restrict__ src,
                                             char* sm, int row, int kbBase) {
    #pragma unroll
    for (int g = 0; g < 4; ++g) {
        float4_t v0 = *reinterpret_cast<const float4_t*>(src + g * 8);
        float4_t v1 = *reinterpret_cast<const float4_t*>(src + g * 8 + 4);
        short8_t h8, l8;
        #pragma unroll
        for (int j = 0; j < 4; ++j) {
            unsigned short hh, ll; split2(v0[j], hh, ll);
            h8[j] = (short)hh; l8[j] = (short)ll;
        }
        #pragma unroll
        for (int j = 0; j < 4; ++j) {
            unsigned short hh, ll; split2(v1[j], hh, ll);
            h8[4 + j] = (short)hh; l8[4 + j] = (short)ll;
        }
        const int off = lds_grp(row, kbBase + g);
        *reinterpret_cast<short8_t*>(sm + off)         = h8;
        *reinterpret_cast<short8_t*>(sm + PLANE + off) = l8;
    }
}

// one hidden layer with explicit 2-stage register prefetch pipeline:
// acc[M 2x32][N 2x32] = act(LDS) @ Wt^T + bias, split-bf16 x3
template <int NKC>
__device__ __forceinline__ void layer_mfma(const char* sm, int lane, int rbase, int nb,
                                           const unsigned short* __restrict__ wHp,
                                           const unsigned short* __restrict__ wLp,
                                           int Kpad, const float* __restrict__ bias,
                                           f32x16 acc[2][2]) {
    const int rl = lane & 31, h = lane >> 5;
    #pragma unroll
    for (int ni = 0; ni < 2; ++ni) {
        const float bv = bias[nb + ni * 32 + rl];
        f32x16 a;
        #pragma unroll
        for (int i = 0; i < 16; ++i) a[i] = bv;
        acc[0][ni] = a; acc[1][ni] = a;
    }
    Frag8 ahP[2][2], alP[2][2], bhP[2][2], blP[2][2];   // [stage][mi/ni]
    // prologue: stage 0 loads (kc = 0)
    {
        #pragma unroll
        for (int mi = 0; mi < 2; ++mi) {
            const int off = lds_grp(rbase + mi * 32 + rl, h);
            ahP[0][mi].s = *reinterpret_cast<const short8_t*>(sm + off);
            alP[0][mi].s = *reinterpret_cast<const short8_t*>(sm + PLANE + off);
        }
        #pragma unroll
        for (int ni = 0; ni < 2; ++ni) {
            const int woff = (nb + ni * 32 + rl) * Kpad + h * 8;
            bhP[0][ni].s = *reinterpret_cast<const short8_t*>(wHp + woff);
            blP[0][ni].s = *reinterpret_cast<const short8_t*>(wLp + woff);
        }
    }
    #pragma unroll
    for (int kc = 0; kc < NKC; ++kc) {
        const int cur = kc & 1, nxt = cur ^ 1;
        if (kc + 1 < NKC) {          // issue next-stage loads before this stage's MFMAs
            const int kb = 2 * (kc + 1) + h;
            #pragma unroll
            for (int mi = 0; mi < 2; ++mi) {
                const int off = lds_grp(rbase + mi * 32 + rl, kb);
                ahP[nxt][mi].s = *reinterpret_cast<const short8_t*>(sm + off);
                alP[nxt][mi].s = *reinterpret_cast<const short8_t*>(sm + PLANE + off);
            }
            #pragma unroll
            for (int ni = 0; ni < 2; ++ni) {
                const int woff = (nb + ni * 32 + rl) * Kpad + (kc + 1) * 16 + h * 8;
                bhP[nxt][ni].s = *reinterpret_cast<const short8_t*>(wHp + woff);
                blP[nxt][ni].s = *reinterpret_cast<const short8_t*>(wLp + woff);
            }
        }
        __builtin_amdgcn_s_setprio(1);
        #pragma unroll
        for (int mi = 0; mi < 2; ++mi)
            #pragma unroll
            for (int ni = 0; ni < 2; ++ni) {
                acc[mi][ni] = __builtin_amdgcn_mfma_f32_32x32x16_bf16(ahP[cur][mi].b, bhP[cur][ni].b, acc[mi][ni], 0, 0, 0);
                acc[mi][ni] = __builtin_amdgcn_mfma_f32_32x32x16_bf16(ahP[cur][mi].b, blP[cur][ni].b, acc[mi][ni], 0, 0, 0);
                acc[mi][ni] = __builtin_amdgcn_mfma_f32_32x32x16_bf16(alP[cur][mi].b, bhP[cur][ni].b, acc[mi][ni], 0, 0, 0);
            }
        __builtin_amdgcn_s_setprio(0);
    }
}

// relu + split + store accumulators back into the (same) act buffer
__device__ __forceinline__ void store_act(char* sm, int lane, int rbase, int nb,
                                          const f32x16 acc[2][2]) {
    const int rl = lane & 31, h = lane >> 5;
    #pragma unroll
    for (int mi = 0; mi < 2; ++mi)
        #pragma unroll
        for (int ni = 0; ni < 2; ++ni) {
            const int k   = nb + ni * 32 + rl;   // output col -> next layer k
            const int kb  = k >> 3;
            const int sub = (k & 7) * 2;
            const int swz = (kb & 7) << 4;
            #pragma unroll
            for (int reg = 0; reg < 16; ++reg) {
                float v = fmaxf(acc[mi][ni][reg], 0.0f);   // ReLU (layers 0..3)
                const int row = rbase + mi * 32 + (reg & 3) + 8 * (reg >> 2) + 4 * h;
                const int off = kb * KBS + ((row * 16) ^ swz) + sub;
                unsigned short hh, ll; split2(v, hh, ll);
                *reinterpret_cast<unsigned short*>(sm + off)         = hh;
                *reinterpret_cast<unsigned short*>(sm + PLANE + off) = ll;
            }
        }
}

// ---------------------------------------------------------------------------

__global__ __launch_bounds__(THREADS, 2)
void liif_main(const float* __restrict__ coord, const float* __restrict__ cell,
               const char* __restrict__ ws,
               const float* __restrict__ b0, const float* __restrict__ b1,
               const float* __restrict__ b2, const float* __restrict__ b3,
               const float* __restrict__ b4, float* __restrict__ out) {
    extern __shared__ char sm[];
    const int tid  = threadIdx.x;
    const int lane = tid & 63;
    const int wid  = tid >> 6;
    const int wm   = wid >> 2, wn = wid & 3;      // 2(M) x 4(N) wave grid
    const int gq0  = blockIdx.x * TM;
    const int bb   = gq0 >> 16;                   // batch (Q = 65536)

    const float* featT = reinterpret_cast<const float*>(ws + OFF_FEATT);
    const float* lrT   = reinterpret_cast<const float*>(ws + OFF_LRT);
    const unsigned short* wt0H = reinterpret_cast<const unsigned short*>(ws + OFF_WT0);
    const unsigned short* wt0L = reinterpret_cast<const unsigned short*>(ws + OFF_WT0 + PS0);
    const unsigned short* wHl[3] = {
        reinterpret_cast<const unsigned short*>(ws + OFF_WT1),
        reinterpret_cast<const unsigned short*>(ws + OFF_WT2),
        reinterpret_cast<const unsigned short*>(ws + OFF_WT3)};
    const unsigned short* wLl[3] = {
        reinterpret_cast<const unsigned short*>(ws + OFF_WT1 + PS1),
        reinterpret_cast<const unsigned short*>(ws + OFF_WT2 + PS1),
        reinterpret_cast<const unsigned short*>(ws + OFF_WT3 + PS1)};
    const float* bls[3] = {b1, b2, b3};

    // ---- prologue: zero the K-pad block (kb 33) and build ensemble weights ----
    for (int i = tid; i < (KBS / 4) * 2; i += THREADS) {
        const int p = i / (KBS / 4);
        const int j = i - p * (KBS / 4);
        *reinterpret_cast<int*>(sm + p * PLANE + 33 * KBS + j * 4) = 0;
    }
    if (tid < TM) {
        const int gq = gq0 + tid;
        const float c0 = coord[2 * gq], c1 = coord[2 * gq + 1];
        float a[4];
        #pragma unroll
        for (int s = 0; s < 4; ++s) {
            int iy, ix, liy, lix; float r0, r1;
            calc_idx(c0, c1, s, iy, ix, liy, lix, r0, r1);
            a[s] = fabsf(r0 * r1) + EPS_AREA;
        }
        const float tot = a[0] + a[1] + a[2] + a[3];
        float* wtab = reinterpret_cast<float*>(sm + LDS_WT);
        #pragma unroll
        for (int s = 0; s < 4; ++s) wtab[s * TM + tid] = a[3 - s] / tot;  // diagonal swap
    }

    f32x16 oacc;
    #pragma unroll
    for (int i = 0; i < 16; ++i) oacc[i] = 0.0f;

    #pragma unroll 1
    for (int s = 0; s < 4; ++s) {
        if (s) __syncthreads();   // prev-shift layer-4 reads done before overwrite

        // ---- gather: build X tile (262-dim, reordered) in hi/lo planes ----
        {
            const int r = tid >> 2, p = tid & 3;   // 4 threads per row, 32 ch each
            const int gq = gq0 + r;
            const float c0 = coord[2 * gq], c1 = coord[2 * gq + 1];
            int iy, ix, liy, lix; float r0, r1;
            calc_idx(c0, c1, s, iy, ix, liy, lix, r0, r1);
            const float* fsrc = featT + (((size_t)(bb * Hc  + iy)  * Wc  + ix)  * Cc + p * 32);
            const float* lsrc = lrT   + (((size_t)(bb * HLc + liy) * WLc + lix) * Cc + p * 32);
            gather_write(fsrc, sm, r, p * 4);        // q_feat  -> k 0..127
            gather_write(lsrc, sm, r, 16 + p * 4);   // lq_feat -> k 128..255
            if (tid < TM) {                          // extras  -> k 256..263 (kb 32)
                const int gq2 = gq0 + tid;
                const float d0 = coord[2 * gq2], d1 = coord[2 * gq2 + 1];
                int jy, jx, ljy, ljx; float s0, s1;
                calc_idx(d0, d1, s, jy, jx, ljy, ljx, s0, s1);
                float vals[8];
                vals[0] = s0;                                       // rel_coord h
                vals[1] = s1;                                       // rel_coord w
                vals[2] = -1.0f + (2.0f * (float)ljy + 1.0f) / (float)HLc;
                vals[3] = -1.0f + (2.0f * (float)ljx + 1.0f) / (float)WLc;
                vals[4] = cell[2 * gq2]     * (float)Hc;            // rel_cell h
                vals[5] = cell[2 * gq2 + 1] * (float)Wc;            // rel_cell w
                vals[6] = 0.0f; vals[7] = 0.0f;
                short8_t h8, l8;
                #pragma unroll
                for (int j = 0; j < 8; ++j) {
                    unsigned short hh, ll; split2(vals[j], hh, ll);
                    h8[j] = (short)hh; l8[j] = (short)ll;
                }
                const int off = 32 * KBS + tid * 16;  // kb=32 -> swizzle slot 0
                *reinterpret_cast<short8_t*>(sm + off)         = h8;
                *reinterpret_cast<short8_t*>(sm + PLANE + off) = l8;
            }
        }
        __syncthreads();

        // ---- layer 0 (K=272 padded) ----
        f32x16 acc[2][2];
        layer_mfma<17>(sm, lane, wm * 64, wn * 64, wt0H, wt0L, K0P, b0, acc);
        __syncthreads();                 // all X reads complete
        store_act(sm, lane, wm * 64, wn * 64, acc);

        // ---- layers 1..3 (K=256) ----
        #pragma unroll
        for (int l = 0; l < 3; ++l) {
            __syncthreads();             // act writes visible
            layer_mfma<16>(sm, lane, wm * 64, wn * 64, wHl[l], wLl[l], 256, bls[l], acc);
            __syncthreads();
            store_act(sm, lane, wm * 64, wn * 64, acc);
        }
        __syncthreads();

        // ---- layer 4 (N=3 padded to 32): waves 0..3, one 32-row tile each ----
        if (wid < 4) {
            const int rl = lane & 31, h = lane >> 5;
            const int rb4 = wid * 32;
            const float bv = (rl < 3) ? b4[rl] : 0.0f;
            f32x16 p4;
            #pragma unroll
            for (int i = 0; i < 16; ++i) p4[i] = bv;
            const unsigned short* w4H = reinterpret_cast<const unsigned short*>(ws + OFF_WT4);
            const unsigned short* w4L = reinterpret_cast<const unsigned short*>(ws + OFF_WT4 + PS4);
            Frag8 a4h[2], a4l[2], b4h[2], b4l[2];
            {
                const int off = lds_grp(rb4 + rl, h);
                a4h[0].s = *reinterpret_cast<const short8_t*>(sm + off);
                a4l[0].s = *reinterpret_cast<const short8_t*>(sm + PLANE + off);
                const int woff = rl * 256 + h * 8;
                b4h[0].s = *reinterpret_cast<const short8_t*>(w4H + woff);
                b4l[0].s = *reinterpret_cast<const short8_t*>(w4L + woff);
            }
            #pragma unroll
            for (int kc = 0; kc < 16; ++kc) {
                const int cur = kc & 1, nxt = cur ^ 1;
                if (kc + 1 < 16) {
                    const int kb = 2 * (kc + 1) + h;
                    const int off = lds_grp(rb4 + rl, kb);
                    a4h[nxt].s = *reinterpret_cast<const short8_t*>(sm + off);
                    a4l[nxt].s = *reinterpret_cast<const short8_t*>(sm + PLANE + off);
                    const int woff = rl * 256 + (kc + 1) * 16 + h * 8;
                    b4h[nxt].s = *reinterpret_cast<const short8_t*>(w4H + woff);
                    b4l[nxt].s = *reinterpret_cast<const short8_t*>(w4L + woff);
                }
                p4 = __builtin_amdgcn_mfma_f32_32x32x16_bf16(a4h[cur].b, b4h[cur].b, p4, 0, 0, 0);
                p4 = __builtin_amdgcn_mfma_f32_32x32x16_bf16(a4h[cur].b, b4l[cur].b, p4, 0, 0, 0);
                p4 = __builtin_amdgcn_mfma_f32_32x32x16_bf16(a4l[cur].b, b4h[cur].b, p4, 0, 0, 0);
            }
            const float* wtab = reinterpret_cast<const float*>(sm + LDS_WT);
            #pragma unroll
            for (int reg = 0; reg < 16; ++reg) {
                const int rloc = (reg & 3) + 8 * (reg >> 2) + 4 * h;
                oacc[reg] += p4[reg] * wtab[s * TM + rb4 + rloc];
            }
        }
    }

    // ---- final store: out[b][q][c], c = lane&31 (valid 0..2) ----
    if (wid < 4) {
        const int col = lane & 31, h = lane >> 5;
        if (col < 3) {
            #pragma unroll
            for (int reg = 0; reg < 16; ++reg) {
                const int row = wid * 32 + (reg & 3) + 8 * (reg >> 2) + 4 * h;
                out[(size_t)(gq0 + row) * 3 + col] = oacc[reg];
            }
        }
    }
}

// ---------------------------------------------------------------------------
// prep kernels
// ---------------------------------------------------------------------------

// [B][C][P] -> [B][P][C], C = 128
__global__ void transpose_cp(const float* __restrict__ in, float* __restrict__ out, int P) {
    __shared__ float tile[32][33];
    const int bz = blockIdx.z;
    const int p0 = blockIdx.x * 32, c0 = blockIdx.y * 32;
    const int tx = threadIdx.x, ty = threadIdx.y;   // 32 x 8
    #pragma unroll
    for (int i = 0; i < 32; i += 8)
        tile[ty + i][tx] = in[((size_t)bz * 128 + c0 + ty + i) * P + p0 + tx];
    __syncthreads();
    #pragma unroll
    for (int i = 0; i < 32; i += 8)
        out[((size_t)bz * P + p0 + ty + i) * 128 + c0 + tx] = tile[tx][ty + i];
}

// build transposed hi/lo bf16 weight planes (layer-0 rows permuted, zero padded)
__global__ void prep_weights(const float* __restrict__ W0, const float* __restrict__ W1,
                             const float* __restrict__ W2, const float* __restrict__ W3,
                             const float* __restrict__ W4, char* __restrict__ ws) {
    const int l = blockIdx.y;
    const int idx = blockIdx.x * 256 + threadIdx.x;
    const int Kpad = (l == 0) ? K0P : 256;
    const int Npad = (l == 4) ? 32  : 256;
    if (idx >= Kpad * Npad) return;
    const int n = idx / Kpad;
    const int k = idx - n * Kpad;
    const int No = (l == 4) ? 3 : 256;
    const float* W = (l == 0) ? W0 : (l == 1) ? W1 : (l == 2) ? W2 : (l == 3) ? W3 : W4;
    float v = 0.0f;
    if (n < No) {
        int ko = -1;
        if (l == 0) {
            // X reorder: [q_feat(0-127), lq_feat(128-255), rel(256,257), lqc(258,259), rcell(260,261)]
            if      (k < 128) ko = k;
            else if (k < 256) ko = k + 2;     // lq_feat was at orig rows 130..257
            else if (k == 256) ko = 128;      // rel_coord h
            else if (k == 257) ko = 129;      // rel_coord w
            else if (k < 262) ko = k;         // lq_coord, rel_cell at orig 258..261
        } else if (k < 256) ko = k;
        if (ko >= 0) v = W[(size_t)ko * No + n];
    }
    size_t off, ps;
    switch (l) {
        case 0:  off = OFF_WT0; ps = PS0; break;
        case 1:  off = OFF_WT1; ps = PS1; break;
        case 2:  off = OFF_WT2; ps = PS1; break;
        case 3:  off = OFF_WT3; ps = PS1; break;
        default: off = OFF_WT4; ps = PS4; break;
    }
    unsigned short hh, ll; split2(v, hh, ll);
    reinterpret_cast<unsigned short*>(ws + off)[(size_t)n * Kpad + k]      = hh;
    reinterpret_cast<unsigned short*>(ws + off + ps)[(size_t)n * Kpad + k] = ll;
}

// ---------------------------------------------------------------------------

extern "C" void kernel_launch(void* const* d_in, const int* in_sizes, int n_in,
                              void* d_out, int out_size, void* d_ws, size_t ws_size,
                              hipStream_t stream) {
    const float* feat  = (const float*)d_in[0];
    const float* lr    = (const float*)d_in[1];
    const float* coord = (const float*)d_in[2];
    const float* cell  = (const float*)d_in[3];
    const float* W0 = (const float*)d_in[4];  const float* b0 = (const float*)d_in[5];
    const float* W1 = (const float*)d_in[6];  const float* b1 = (const float*)d_in[7];
    const float* W2 = (const float*)d_in[8];  const float* b2 = (const float*)d_in[9];
    const float* W3 = (const float*)d_in[10]; const float* b3 = (const float*)d_in[11];
    const float* W4 = (const float*)d_in[12]; const float* b4 = (const float*)d_in[13];
    char*  ws  = (char*)d_ws;
    float* out = (float*)d_out;

    dim3 bt(32, 8);
    transpose_cp<<<dim3(Hc * Wc / 32, Cc / 32, Bc), bt, 0, stream>>>(
        feat, (float*)(ws + OFF_FEATT), Hc * Wc);
    transpose_cp<<<dim3(HLc * WLc / 32, Cc / 32, Bc), bt, 0, stream>>>(
        lr, (float*)(ws + OFF_LRT), HLc * WLc);
    prep_weights<<<dim3((K0P * 256 + 255) / 256, 5), 256, 0, stream>>>(W0, W1, W2, W3, W4, ws);

    hipFuncSetAttribute(reinterpret_cast<const void*>(liif_main),
                        hipFuncAttributeMaxDynamicSharedMemorySize, LDS_TOTAL);
    const int nblocks = (Bc * 65536) / TM;   // 1024
    liif_main<<<nblocks, THREADS, LDS_TOTAL, stream>>>(
        coord, cell, ws, b0, b1, b2, b3, b4, out);
}

// Round 5
// 2219.023 us; speedup vs baseline: 2.2325x; 2.2325x over previous
//
#include <hip/hip_runtime.h>
#include <hip/hip_bf16.h>

// ---------------------------------------------------------------------------
// LIIF query_image fused kernel for MI355X (gfx950).  Round 5.
// Split-precision bf16 MFMA (hi/lo, 3 products) ~= fp32 accuracy.
// R5 vs R3: (1) fragment-packed weight layout -> each wave B-load is one
// coalesced 1KB dwordx4 (was 32 scattered cache lines); (2) nontemporal
// feat-gather loads (protect weight set in L2); (3) register-lean simple
// K-loop (ni-sequential, no 2-stage prefetch) -> fits 128 VGPR, no spill.
// ---------------------------------------------------------------------------

typedef __attribute__((ext_vector_type(8)))  short   short8_t;
typedef __attribute__((ext_vector_type(8)))  __bf16  bf16x8;
typedef __attribute__((ext_vector_type(16))) float   f32x16;
typedef __attribute__((ext_vector_type(4)))  float   float4_t;

union Frag8 { short8_t s; bf16x8 b; };

#define EPS_SHIFT 1e-6f
#define EPS_AREA  1e-9f

constexpr int Bc = 2, Cc = 128, Hc = 128, Wc = 128, HLc = 64, WLc = 64;
constexpr int K0P = 272;          // layer0 K padded: 262 -> 272 (17 k-chunks of 16)
constexpr int TM = 128;           // queries per block
constexpr int THREADS = 512;      // 8 waves: 2(M) x 4(N)
constexpr int NKB = K0P / 8;      // 34 k-blocks of 8 in act buffer
constexpr int KBS = TM * 16;      // 2048 B per k-block per plane
constexpr int PLANE = NKB * KBS;  // 69632 B  (hi plane; lo plane follows)
constexpr int LDS_WT = 2 * PLANE;              // offset of weight table
constexpr int LDS_TOTAL = LDS_WT + 4 * TM * 4; // + wtab[4][128] = 141312 B

// workspace layout
constexpr size_t OFF_FEATT = 0;
constexpr size_t SZ_FEATT  = (size_t)Bc * Hc * Wc * Cc * 4;    // 16 MB
constexpr size_t OFF_LRT   = OFF_FEATT + SZ_FEATT;
constexpr size_t SZ_LRT    = (size_t)Bc * HLc * WLc * Cc * 4;  // 4 MB
constexpr size_t OFF_WT0   = OFF_LRT + SZ_LRT;
constexpr size_t PS0       = (size_t)256 * K0P * 2;            // per-plane bytes
constexpr size_t OFF_WT1   = OFF_WT0 + 2 * PS0;
constexpr size_t PS1       = (size_t)256 * 256 * 2;
constexpr size_t OFF_WT2   = OFF_WT1 + 2 * PS1;
constexpr size_t OFF_WT3   = OFF_WT2 + 2 * PS1;
constexpr size_t OFF_WT4   = OFF_WT3 + 2 * PS1;
constexpr size_t PS4       = (size_t)32 * 256 * 2;

// ---------------------------------------------------------------------------

__device__ __forceinline__ unsigned short bf16_rne(float x) {
    unsigned u = __float_as_uint(x);
    unsigned r = (u + 0x7FFFu + ((u >> 16) & 1u)) >> 16;
    return (unsigned short)r;
}

// x = hi + lo + eps, |eps| ~ 2^-17 |x|.  hi = truncated bf16, lo = rne(bf16(rem)).
__device__ __forceinline__ void split2(float v, unsigned short& hi, unsigned short& lo) {
    unsigned u = __float_as_uint(v) & 0xFFFF0000u;
    hi = (unsigned short)(u >> 16);
    lo = bf16_rne(v - __uint_as_float(u));
}

// byte offset of the 8-k group (row, kb) inside a plane (swizzled)
__device__ __forceinline__ int lds_grp(int row, int kb) {
    return kb * KBS + ((row * 16) ^ ((kb & 7) << 4));
}

// nearest-gather index math, exactly mirroring the reference formulas
__device__ __forceinline__ void calc_idx(float c0, float c1, int s,
                                         int& iy, int& ix, int& liy, int& lix,
                                         float& rel0, float& rel1) {
    const float rx = 1.0f / Hc, ry = 1.0f / Wc;
    const float vx = (s & 2) ? 1.0f : -1.0f;   // s: 0..3 = (vx,vy) in (-1,-1),(-1,1),(1,-1),(1,1)
    const float vy = (s & 1) ? 1.0f : -1.0f;
    const float sh0 = vx * rx + EPS_SHIFT;
    const float sh1 = vy * ry + EPS_SHIFT;
    float cc0 = fminf(fmaxf(c0 + sh0, -1.0f + 1e-6f), 1.0f - 1e-6f);
    float cc1 = fminf(fmaxf(c1 + sh1, -1.0f + 1e-6f), 1.0f - 1e-6f);
    iy  = min(max((int)floorf(((cc0 + 1.0f) * (float)Hc  - 1.0f) * 0.5f + 0.5f), 0), Hc  - 1);
    ix  = min(max((int)floorf(((cc1 + 1.0f) * (float)Wc  - 1.0f) * 0.5f + 0.5f), 0), Wc  - 1);
    liy = min(max((int)floorf(((cc0 + 1.0f) * (float)HLc - 1.0f) * 0.5f + 0.5f), 0), HLc - 1);
    lix = min(max((int)floorf(((cc1 + 1.0f) * (float)WLc - 1.0f) * 0.5f + 0.5f), 0), WLc - 1);
    const float qc0 = -1.0f + (2.0f * (float)iy + 1.0f) / (float)Hc;
    const float qc1 = -1.0f + (2.0f * (float)ix + 1.0f) / (float)Wc;
    rel0 = (c0 - qc0) * (float)Hc;   // rel uses ORIGINAL coord
    rel1 = (c1 - qc1) * (float)Wc;
}

template <bool NT>
__device__ __forceinline__ float4_t ld4(const float* p) {
    if (NT) return __builtin_nontemporal_load(reinterpret_cast<const float4_t*>(p));
    return *reinterpret_cast<const float4_t*>(p);
}

// gather 32 contiguous channels (NHWC) -> hi/lo planes at k-blocks kbBase..+3
template <bool NT>
__device__ __forceinline__ void gather_write(const float* __restrict__ src,
                                             char* sm, int row, int kbBase) {
    #pragma unroll
    for (int g = 0; g < 4; ++g) {
        float4_t v0 = ld4<NT>(src + g * 8);
        float4_t v1 = ld4<NT>(src + g * 8 + 4);
        short8_t h8, l8;
        #pragma unroll
        for (int j = 0; j < 4; ++j) {
            unsigned short hh, ll; split2(v0[j], hh, ll);
            h8[j] = (short)hh; l8[j] = (short)ll;
        }
        #pragma unroll
        for (int j = 0; j < 4; ++j) {
            unsigned short hh, ll; split2(v1[j], hh, ll);
            h8[4 + j] = (short)hh; l8[4 + j] = (short)ll;
        }
        const int off = lds_grp(row, kbBase + g);
        *reinterpret_cast<short8_t*>(sm + off)         = h8;
        *reinterpret_cast<short8_t*>(sm + PLANE + off) = l8;
    }
}

// one hidden layer, register-lean: acc[M 2x32][N 2x32] = act(LDS) @ Wt + bias.
// Weights are fragment-packed: byte offset of a wave's frag = ((g*NKC+kc)*64+lane)*16
template <int NKC>
__device__ __forceinline__ void layer_mfma(const char* sm, int lane, int rbase, int wn,
                                           const unsigned short* __restrict__ wHp,
                                           const unsigned short* __restrict__ wLp,
                                           const float* __restrict__ bias,
                                           f32x16 acc[2][2]) {
    const int rl = lane & 31, h = lane >> 5;
    #pragma unroll
    for (int ni = 0; ni < 2; ++ni) {
        const float bv = bias[wn * 64 + ni * 32 + rl];
        f32x16 a;
        #pragma unroll
        for (int i = 0; i < 16; ++i) a[i] = bv;
        acc[0][ni] = a; acc[1][ni] = a;
    }
    #pragma unroll 2
    for (int kc = 0; kc < NKC; ++kc) {
        const int kb = 2 * kc + h;
        Frag8 ah[2], al[2];
        #pragma unroll
        for (int mi = 0; mi < 2; ++mi) {
            const int off = lds_grp(rbase + mi * 32 + rl, kb);
            ah[mi].s = *reinterpret_cast<const short8_t*>(sm + off);
            al[mi].s = *reinterpret_cast<const short8_t*>(sm + PLANE + off);
        }
        #pragma unroll
        for (int ni = 0; ni < 2; ++ni) {
            const int g = wn * 2 + ni;
            const size_t wo = (size_t)((g * NKC + kc) * 64 + lane) * 8;
            Frag8 bh, bl;
            bh.s = *reinterpret_cast<const short8_t*>(wHp + wo);
            bl.s = *reinterpret_cast<const short8_t*>(wLp + wo);
            __builtin_amdgcn_s_setprio(1);
            #pragma unroll
            for (int mi = 0; mi < 2; ++mi)
                acc[mi][ni] = __builtin_amdgcn_mfma_f32_32x32x16_bf16(ah[mi].b, bh.b, acc[mi][ni], 0, 0, 0);
            #pragma unroll
            for (int mi = 0; mi < 2; ++mi)
                acc[mi][ni] = __builtin_amdgcn_mfma_f32_32x32x16_bf16(ah[mi].b, bl.b, acc[mi][ni], 0, 0, 0);
            #pragma unroll
            for (int mi = 0; mi < 2; ++mi)
                acc[mi][ni] = __builtin_amdgcn_mfma_f32_32x32x16_bf16(al[mi].b, bh.b, acc[mi][ni], 0, 0, 0);
            __builtin_amdgcn_s_setprio(0);
        }
    }
}

// relu + split + store accumulators back into the (same) act buffer
__device__ __forceinline__ void store_act(char* sm, int lane, int rbase, int nb,
                                          const f32x16 acc[2][2]) {
    const int rl = lane & 31, h = lane >> 5;
    #pragma unroll
    for (int mi = 0; mi < 2; ++mi)
        #pragma unroll
        for (int ni = 0; ni < 2; ++ni) {
            const int k   = nb + ni * 32 + rl;   // output col -> next layer k
            const int kb  = k >> 3;
            const int sub = (k & 7) * 2;
            const int swz = (kb & 7) << 4;
            #pragma unroll
            for (int reg = 0; reg < 16; ++reg) {
                float v = fmaxf(acc[mi][ni][reg], 0.0f);   // ReLU (layers 0..3)
                const int row = rbase + mi * 32 + (reg & 3) + 8 * (reg >> 2) + 4 * h;
                const int off = kb * KBS + ((row * 16) ^ swz) + sub;
                unsigned short hh, ll; split2(v, hh, ll);
                *reinterpret_cast<unsigned short*>(sm + off)         = hh;
                *reinterpret_cast<unsigned short*>(sm + PLANE + off) = ll;
            }
        }
}

// ---------------------------------------------------------------------------

__global__ __launch_bounds__(THREADS, 2)
void liif_main(const float* __restrict__ coord, const float* __restrict__ cell,
               const char* __restrict__ ws,
               const float* __restrict__ b0, const float* __restrict__ b1,
               const float* __restrict__ b2, const float* __restrict__ b3,
               const float* __restrict__ b4, float* __restrict__ out) {
    extern __shared__ char sm[];
    const int tid  = threadIdx.x;
    const int lane = tid & 63;
    const int wid  = tid >> 6;
    const int wm   = wid >> 2, wn = wid & 3;      // 2(M) x 4(N) wave grid
    const int gq0  = blockIdx.x * TM;
    const int bb   = gq0 >> 16;                   // batch (Q = 65536)

    const float* featT = reinterpret_cast<const float*>(ws + OFF_FEATT);
    const float* lrT   = reinterpret_cast<const float*>(ws + OFF_LRT);
    const unsigned short* wt0H = reinterpret_cast<const unsigned short*>(ws + OFF_WT0);
    const unsigned short* wt0L = reinterpret_cast<const unsigned short*>(ws + OFF_WT0 + PS0);
    const unsigned short* wHl[3] = {
        reinterpret_cast<const unsigned short*>(ws + OFF_WT1),
        reinterpret_cast<const unsigned short*>(ws + OFF_WT2),
        reinterpret_cast<const unsigned short*>(ws + OFF_WT3)};
    const unsigned short* wLl[3] = {
        reinterpret_cast<const unsigned short*>(ws + OFF_WT1 + PS1),
        reinterpret_cast<const unsigned short*>(ws + OFF_WT2 + PS1),
        reinterpret_cast<const unsigned short*>(ws + OFF_WT3 + PS1)};
    const float* bls[3] = {b1, b2, b3};

    // ---- prologue: zero the K-pad block (kb 33) and build ensemble weights ----
    for (int i = tid; i < (KBS / 4) * 2; i += THREADS) {
        const int p = i / (KBS / 4);
        const int j = i - p * (KBS / 4);
        *reinterpret_cast<int*>(sm + p * PLANE + 33 * KBS + j * 4) = 0;
    }
    if (tid < TM) {
        const int gq = gq0 + tid;
        const float c0 = coord[2 * gq], c1 = coord[2 * gq + 1];
        float a[4];
        #pragma unroll
        for (int s = 0; s < 4; ++s) {
            int iy, ix, liy, lix; float r0, r1;
            calc_idx(c0, c1, s, iy, ix, liy, lix, r0, r1);
            a[s] = fabsf(r0 * r1) + EPS_AREA;
        }
        const float tot = a[0] + a[1] + a[2] + a[3];
        float* wtab = reinterpret_cast<float*>(sm + LDS_WT);
        #pragma unroll
        for (int s = 0; s < 4; ++s) wtab[s * TM + tid] = a[3 - s] / tot;  // diagonal swap
    }

    f32x16 oacc;
    #pragma unroll
    for (int i = 0; i < 16; ++i) oacc[i] = 0.0f;

    #pragma unroll 1
    for (int s = 0; s < 4; ++s) {
        if (s) __syncthreads();   // prev-shift layer-4 reads done before overwrite

        // ---- gather: build X tile (262-dim, reordered) in hi/lo planes ----
        {
            const int r = tid >> 2, p = tid & 3;   // 4 threads per row, 32 ch each
            const int gq = gq0 + r;
            const float c0 = coord[2 * gq], c1 = coord[2 * gq + 1];
            int iy, ix, liy, lix; float r0, r1;
            calc_idx(c0, c1, s, iy, ix, liy, lix, r0, r1);
            const float* fsrc = featT + (((size_t)(bb * Hc  + iy)  * Wc  + ix)  * Cc + p * 32);
            const float* lsrc = lrT   + (((size_t)(bb * HLc + liy) * WLc + lix) * Cc + p * 32);
            gather_write<true >(fsrc, sm, r, p * 4);      // q_feat  -> k 0..127 (nt: 16MB stream)
            gather_write<false>(lsrc, sm, r, 16 + p * 4); // lq_feat -> k 128..255 (L2-resident)
            if (tid < TM) {                               // extras  -> k 256..263 (kb 32)
                const int gq2 = gq0 + tid;
                const float d0 = coord[2 * gq2], d1 = coord[2 * gq2 + 1];
                int jy, jx, ljy, ljx; float s0, s1;
                calc_idx(d0, d1, s, jy, jx, ljy, ljx, s0, s1);
                float vals[8];
                vals[0] = s0;                                       // rel_coord h
                vals[1] = s1;                                       // rel_coord w
                vals[2] = -1.0f + (2.0f * (float)ljy + 1.0f) / (float)HLc;
                vals[3] = -1.0f + (2.0f * (float)ljx + 1.0f) / (float)WLc;
                vals[4] = cell[2 * gq2]     * (float)Hc;            // rel_cell h
                vals[5] = cell[2 * gq2 + 1] * (float)Wc;            // rel_cell w
                vals[6] = 0.0f; vals[7] = 0.0f;
                short8_t h8, l8;
                #pragma unroll
                for (int j = 0; j < 8; ++j) {
                    unsigned short hh, ll; split2(vals[j], hh, ll);
                    h8[j] = (short)hh; l8[j] = (short)ll;
                }
                const int off = 32 * KBS + tid * 16;  // kb=32 -> swizzle slot 0
                *reinterpret_cast<short8_t*>(sm + off)         = h8;
                *reinterpret_cast<short8_t*>(sm + PLANE + off) = l8;
            }
        }
        __syncthreads();

        // ---- layer 0 (K=272 padded) ----
        f32x16 acc[2][2];
        layer_mfma<17>(sm, lane, wm * 64, wn, wt0H, wt0L, b0, acc);
        __syncthreads();                 // all X reads complete
        store_act(sm, lane, wm * 64, wn * 64, acc);

        // ---- layers 1..3 (K=256) ----
        #pragma unroll
        for (int l = 0; l < 3; ++l) {
            __syncthreads();             // act writes visible
            layer_mfma<16>(sm, lane, wm * 64, wn, wHl[l], wLl[l], bls[l], acc);
            __syncthreads();
            store_act(sm, lane, wm * 64, wn * 64, acc);
        }
        __syncthreads();

        // ---- layer 4 (N=3 padded to 32): waves 0..3, one 32-row tile each ----
        if (wid < 4) {
            const int rl = lane & 31, h = lane >> 5;
            const int rb4 = wid * 32;
            const float bv = (rl < 3) ? b4[rl] : 0.0f;
            f32x16 p4;
            #pragma unroll
            for (int i = 0; i < 16; ++i) p4[i] = bv;
            const unsigned short* w4H = reinterpret_cast<const unsigned short*>(ws + OFF_WT4);
            const unsigned short* w4L = reinterpret_cast<const unsigned short*>(ws + OFF_WT4 + PS4);
            #pragma unroll 2
            for (int kc = 0; kc < 16; ++kc) {
                const int kb = 2 * kc + h;
                const int off = lds_grp(rb4 + rl, kb);
                Frag8 ah, al, bh, bl;
                ah.s = *reinterpret_cast<const short8_t*>(sm + off);
                al.s = *reinterpret_cast<const short8_t*>(sm + PLANE + off);
                const size_t wo = (size_t)(kc * 64 + lane) * 8;   // g = 0
                bh.s = *reinterpret_cast<const short8_t*>(w4H + wo);
                bl.s = *reinterpret_cast<const short8_t*>(w4L + wo);
                p4 = __builtin_amdgcn_mfma_f32_32x32x16_bf16(ah.b, bh.b, p4, 0, 0, 0);
                p4 = __builtin_amdgcn_mfma_f32_32x32x16_bf16(ah.b, bl.b, p4, 0, 0, 0);
                p4 = __builtin_amdgcn_mfma_f32_32x32x16_bf16(al.b, bh.b, p4, 0, 0, 0);
            }
            const float* wtab = reinterpret_cast<const float*>(sm + LDS_WT);
            #pragma unroll
            for (int reg = 0; reg < 16; ++reg) {
                const int rloc = (reg & 3) + 8 * (reg >> 2) + 4 * h;
                oacc[reg] += p4[reg] * wtab[s * TM + rb4 + rloc];
            }
        }
    }

    // ---- final store: out[b][q][c], c = lane&31 (valid 0..2) ----
    if (wid < 4) {
        const int col = lane & 31, h = lane >> 5;
        if (col < 3) {
            #pragma unroll
            for (int reg = 0; reg < 16; ++reg) {
                const int row = wid * 32 + (reg & 3) + 8 * (reg >> 2) + 4 * h;
                out[(size_t)(gq0 + row) * 3 + col] = oacc[reg];
            }
        }
    }
}

// ---------------------------------------------------------------------------
// prep kernels
// ---------------------------------------------------------------------------

// [B][C][P] -> [B][P][C], C = 128
__global__ void transpose_cp(const float* __restrict__ in, float* __restrict__ out, int P) {
    __shared__ float tile[32][33];
    const int bz = blockIdx.z;
    const int p0 = blockIdx.x * 32, c0 = blockIdx.y * 32;
    const int tx = threadIdx.x, ty = threadIdx.y;   // 32 x 8
    #pragma unroll
    for (int i = 0; i < 32; i += 8)
        tile[ty + i][tx] = in[((size_t)bz * 128 + c0 + ty + i) * P + p0 + tx];
    __syncthreads();
    #pragma unroll
    for (int i = 0; i < 32; i += 8)
        out[((size_t)bz * P + p0 + ty + i) * 128 + c0 + tx] = tile[tx][ty + i];
}

// build fragment-packed hi/lo bf16 weight planes (layer-0 rows permuted, zero padded)
// packed elem offset = ((g*(Kpad/16) + kc)*64 + h*32 + rl)*8 + j
//   g = n>>5, rl = n&31, kc = k>>4, h = (k>>3)&1, j = k&7
__global__ void prep_weights(const float* __restrict__ W0, const float* __restrict__ W1,
                             const float* __restrict__ W2, const float* __restrict__ W3,
                             const float* __restrict__ W4, char* __restrict__ ws) {
    const int l = blockIdx.y;
    const int idx = blockIdx.x * 256 + threadIdx.x;
    const int Kpad = (l == 0) ? K0P : 256;
    const int Npad = (l == 4) ? 32  : 256;
    if (idx >= Kpad * Npad) return;
    const int n = idx / Kpad;
    const int k = idx - n * Kpad;
    const int No = (l == 4) ? 3 : 256;
    const float* W = (l == 0) ? W0 : (l == 1) ? W1 : (l == 2) ? W2 : (l == 3) ? W3 : W4;
    float v = 0.0f;
    if (n < No) {
        int ko = -1;
        if (l == 0) {
            // X reorder: [q_feat(0-127), lq_feat(128-255), rel(256,257), lqc(258,259), rcell(260,261)]
            if      (k < 128) ko = k;
            else if (k < 256) ko = k + 2;     // lq_feat was at orig rows 130..257
            else if (k == 256) ko = 128;      // rel_coord h
            else if (k == 257) ko = 129;      // rel_coord w
            else if (k < 262) ko = k;         // lq_coord, rel_cell at orig 258..261
        } else if (k < 256) ko = k;
        if (ko >= 0) v = W[(size_t)ko * No + n];
    }
    size_t off, ps;
    switch (l) {
        case 0:  off = OFF_WT0; ps = PS0; break;
        case 1:  off = OFF_WT1; ps = PS1; break;
        case 2:  off = OFF_WT2; ps = PS1; break;
        case 3:  off = OFF_WT3; ps = PS1; break;
        default: off = OFF_WT4; ps = PS4; break;
    }
    const int g = n >> 5, rl = n & 31;
    const int kc = k >> 4, hbit = (k >> 3) & 1, j = k & 7;
    const size_t poff = ((size_t)((g * (Kpad >> 4) + kc) * 64 + hbit * 32 + rl)) * 8 + j;
    unsigned short hh, ll; split2(v, hh, ll);
    reinterpret_cast<unsigned short*>(ws + off)[poff]      = hh;
    reinterpret_cast<unsigned short*>(ws + off + ps)[poff] = ll;
}

// ---------------------------------------------------------------------------

extern "C" void kernel_launch(void* const* d_in, const int* in_sizes, int n_in,
                              void* d_out, int out_size, void* d_ws, size_t ws_size,
                              hipStream_t stream) {
    const float* feat  = (const float*)d_in[0];
    const float* lr    = (const float*)d_in[1];
    const float* coord = (const float*)d_in[2];
    const float* cell  = (const float*)d_in[3];
    const float* W0 = (const float*)d_in[4];  const float* b0 = (const float*)d_in[5];
    const float* W1 = (const float*)d_in[6];  const float* b1 = (const float*)d_in[7];
    const float* W2 = (const float*)d_in[8];  const float* b2 = (const float*)d_in[9];
    const float* W3 = (const float*)d_in[10]; const float* b3 = (const float*)d_in[11];
    const float* W4 = (const float*)d_in[12]; const float* b4 = (const float*)d_in[13];
    char*  ws  = (char*)d_ws;
    float* out = (float*)d_out;

    dim3 bt(32, 8);
    transpose_cp<<<dim3(Hc * Wc / 32, Cc / 32, Bc), bt, 0, stream>>>(
        feat, (float*)(ws + OFF_FEATT), Hc * Wc);
    transpose_cp<<<dim3(HLc * WLc / 32, Cc / 32, Bc), bt, 0, stream>>>(
        lr, (float*)(ws + OFF_LRT), HLc * WLc);
    prep_weights<<<dim3((K0P * 256 + 255) / 256, 5), 256, 0, stream>>>(W0, W1, W2, W3, W4, ws);

    hipFuncSetAttribute(reinterpret_cast<const void*>(liif_main),
                        hipFuncAttributeMaxDynamicSharedMemorySize, LDS_TOTAL);
    const int nblocks = (Bc * 65536) / TM;   // 1024
    liif_main<<<nblocks, THREADS, LDS_TOTAL, stream>>>(
        coord, cell, ws, b0, b1, b2, b3, b4, out);
}